// Round 1
// baseline (130.161 us; speedup 1.0000x reference)
//
#include <hip/hip_runtime.h>

#define BB 2
#define SS 1024
#define DD 256
#define QBLK 8

// ---------------------------------------------------------------------------
// Kernel A: Q = x@Wq.T + bq, K = ..., V = ...; also qq[row]=|Q_row|^2, kk=|K_row|^2
// One block = 8 rows of x. Thread t owns output column t for all 8 rows,
// so each weight row Wq[t,:] is loaded once (float4) and reused 8x.
// ---------------------------------------------------------------------------
__global__ __launch_bounds__(256) void qkv_kernel(
    const float* __restrict__ x,
    const float* __restrict__ Wq, const float* __restrict__ bq,
    const float* __restrict__ Wk, const float* __restrict__ bk,
    const float* __restrict__ Wv, const float* __restrict__ bv,
    float* __restrict__ Q, float* __restrict__ K, float* __restrict__ V,
    float* __restrict__ qq, float* __restrict__ kk)
{
    __shared__ float xs[QBLK][DD];
    __shared__ float redq[QBLK][4];
    __shared__ float redk[QBLK][4];

    const int t = threadIdx.x;
    const int row0 = blockIdx.x * QBLK;

    // stage 8 x-rows: 2048 floats = 512 float4, coalesced
    {
        const float4* xg = (const float4*)(x + (size_t)row0 * DD);
        float4* xs4 = (float4*)&xs[0][0];
        xs4[t] = xg[t];
        xs4[t + 256] = xg[t + 256];
    }
    __syncthreads();

    float aq[QBLK], ak[QBLK], av[QBLK];
#pragma unroll
    for (int r = 0; r < QBLK; ++r) { aq[r] = 0.f; ak[r] = 0.f; av[r] = 0.f; }

    const float4* wq4 = (const float4*)(Wq + (size_t)t * DD);
    const float4* wk4 = (const float4*)(Wk + (size_t)t * DD);
    const float4* wv4 = (const float4*)(Wv + (size_t)t * DD);
    const float4* xsv = (const float4*)&xs[0][0]; // row r starts at r*64

    for (int d4 = 0; d4 < DD / 4; ++d4) {
        float4 wq = wq4[d4];
        float4 wk = wk4[d4];
        float4 wv = wv4[d4];
#pragma unroll
        for (int r = 0; r < QBLK; ++r) {
            float4 xv = xsv[r * (DD / 4) + d4]; // uniform address -> LDS broadcast
            aq[r] = fmaf(xv.x, wq.x, aq[r]);
            aq[r] = fmaf(xv.y, wq.y, aq[r]);
            aq[r] = fmaf(xv.z, wq.z, aq[r]);
            aq[r] = fmaf(xv.w, wq.w, aq[r]);
            ak[r] = fmaf(xv.x, wk.x, ak[r]);
            ak[r] = fmaf(xv.y, wk.y, ak[r]);
            ak[r] = fmaf(xv.z, wk.z, ak[r]);
            ak[r] = fmaf(xv.w, wk.w, ak[r]);
            av[r] = fmaf(xv.x, wv.x, av[r]);
            av[r] = fmaf(xv.y, wv.y, av[r]);
            av[r] = fmaf(xv.z, wv.z, av[r]);
            av[r] = fmaf(xv.w, wv.w, av[r]);
        }
    }

    const float bqv = bq[t], bkv = bk[t], bvv = bv[t];
    float sq[QBLK], sk[QBLK];
#pragma unroll
    for (int r = 0; r < QBLK; ++r) {
        float qv = aq[r] + bqv;
        float kv = ak[r] + bkv;
        float vv = av[r] + bvv;
        Q[(size_t)(row0 + r) * DD + t] = qv;
        K[(size_t)(row0 + r) * DD + t] = kv;
        V[(size_t)(row0 + r) * DD + t] = vv;
        sq[r] = qv * qv;
        sk[r] = kv * kv;
    }

    // block-reduce the 8 row norms (wave shuffle, then 4 wave partials in LDS)
    const int wave = t >> 6;
    const int lane = t & 63;
#pragma unroll
    for (int r = 0; r < QBLK; ++r) {
        float vq = sq[r];
        float vk = sk[r];
#pragma unroll
        for (int o = 32; o > 0; o >>= 1) {
            vq += __shfl_xor(vq, o, 64);
            vk += __shfl_xor(vk, o, 64);
        }
        if (lane == 0) { redq[r][wave] = vq; redk[r][wave] = vk; }
    }
    __syncthreads();
    if (t < QBLK) {
        qq[row0 + t] = redq[t][0] + redq[t][1] + redq[t][2] + redq[t][3];
        kk[row0 + t] = redk[t][0] + redk[t][1] + redk[t][2] + redk[t][3];
    }
}

// ---------------------------------------------------------------------------
// Kernel B: fused attention + output projection.
// One block = 8 query rows of one batch. 256 threads (4 waves).
// Phase 1: scores s[q][k] = -sqrt(max(|Q|^2+|K|^2-2 Q.K, 0))/16.
//          Each thread owns 2 k-rows (read from global exactly once per block)
//          and accumulates 8 q dot-products from LDS-broadcast Q.
// Phase 2: softmax per q-row (32-lane groups), unnormalized exp + 1/sum.
// Phase 3: PV: wave w handles k in [w*256,(w+1)*256), coalesced float4 V reads,
//          partials reduced through LDS.
// Phase 4: out = att @ Wo.T + bo (same reuse pattern as kernel A).
// ---------------------------------------------------------------------------
__global__ __launch_bounds__(256) void attn_kernel(
    const float* __restrict__ Q, const float* __restrict__ K,
    const float* __restrict__ V,
    const float* __restrict__ qq, const float* __restrict__ kk,
    const float* __restrict__ Wo, const float* __restrict__ bo,
    float* __restrict__ out)
{
    __shared__ float q_s[QBLK][DD];  // Q rows; reused as attended rows later
    __shared__ float s_s[QBLK][SS];  // scores -> exp(p); reused as PV partials
    __shared__ float qq_s[QBLK];
    __shared__ float inv_s[QBLK];

    const int t = threadIdx.x;
    const int b = blockIdx.x >> 7;            // 128 q-tiles per batch
    const int q0 = (blockIdx.x & 127) * QBLK;
    const int rowbase = b * SS + q0;

    // stage Q rows (coalesced) + norms
    {
        const float4* qg = (const float4*)(Q + (size_t)rowbase * DD);
        float4* qs4 = (float4*)&q_s[0][0];
        qs4[t] = qg[t];
        qs4[t + 256] = qg[t + 256];
        if (t < QBLK) qq_s[t] = qq[rowbase + t];
    }
    __syncthreads();

    const float inv_sqrt_d = 0.0625f; // 1/sqrt(256)

    // ---- Phase 1: scores ----
    {
        const float4* qsv = (const float4*)&q_s[0][0];
#pragma unroll
        for (int pass = 0; pass < 2; ++pass) {
            const int ka = pass * 512 + t;
            const int kb = ka + 256;
            const float4* Ka = (const float4*)(K + (size_t)(b * SS + ka) * DD);
            const float4* Kb = (const float4*)(K + (size_t)(b * SS + kb) * DD);
            float da[QBLK], db[QBLK];
#pragma unroll
            for (int r = 0; r < QBLK; ++r) { da[r] = 0.f; db[r] = 0.f; }

            for (int d4 = 0; d4 < DD / 4; ++d4) {
                float4 va = Ka[d4];
                float4 vb = Kb[d4];
#pragma unroll
                for (int r = 0; r < QBLK; ++r) {
                    float4 qv = qsv[r * (DD / 4) + d4]; // broadcast
                    da[r] = fmaf(qv.x, va.x, da[r]);
                    da[r] = fmaf(qv.y, va.y, da[r]);
                    da[r] = fmaf(qv.z, va.z, da[r]);
                    da[r] = fmaf(qv.w, va.w, da[r]);
                    db[r] = fmaf(qv.x, vb.x, db[r]);
                    db[r] = fmaf(qv.y, vb.y, db[r]);
                    db[r] = fmaf(qv.z, vb.z, db[r]);
                    db[r] = fmaf(qv.w, vb.w, db[r]);
                }
            }
            const float kka = kk[b * SS + ka];
            const float kkb = kk[b * SS + kb];
#pragma unroll
            for (int r = 0; r < QBLK; ++r) {
                float d2a = fmaxf(qq_s[r] + kka - 2.f * da[r], 0.f);
                float d2b = fmaxf(qq_s[r] + kkb - 2.f * db[r], 0.f);
                s_s[r][ka] = -sqrtf(d2a) * inv_sqrt_d;
                s_s[r][kb] = -sqrtf(d2b) * inv_sqrt_d;
            }
        }
    }
    __syncthreads();

    // ---- Phase 2: per-row softmax (unnormalized; store 1/sum) ----
    {
        const int r = t >> 5;
        const int l = t & 31;
        float m = -1e30f;
#pragma unroll 8
        for (int j = 0; j < 32; ++j) m = fmaxf(m, s_s[r][l + 32 * j]);
#pragma unroll
        for (int o = 16; o > 0; o >>= 1) m = fmaxf(m, __shfl_xor(m, o, 32));
        float sum = 0.f;
#pragma unroll 8
        for (int j = 0; j < 32; ++j) {
            const int idx = l + 32 * j;
            float e = __expf(s_s[r][idx] - m);
            s_s[r][idx] = e;
            sum += e;
        }
#pragma unroll
        for (int o = 16; o > 0; o >>= 1) sum += __shfl_xor(sum, o, 32);
        if (l == 0) inv_s[r] = 1.f / sum;
    }
    __syncthreads();

    // ---- Phase 3: PV (4-wave k-split, coalesced V) ----
    {
        const int kg = t >> 6;  // wave id: k range [kg*256, kg*256+256)
        const int dl = t & 63;  // float4 column
        const float4* V4 = (const float4*)(V + (size_t)b * SS * DD);
        float4 acc[QBLK];
#pragma unroll
        for (int r = 0; r < QBLK; ++r) acc[r] = make_float4(0.f, 0.f, 0.f, 0.f);

        for (int kj = 0; kj < 256; ++kj) {
            const int k = kg * 256 + kj;
            float4 v = V4[(size_t)k * (DD / 4) + dl];
#pragma unroll
            for (int r = 0; r < QBLK; ++r) {
                float p = s_s[r][k]; // uniform within wave -> broadcast
                acc[r].x = fmaf(p, v.x, acc[r].x);
                acc[r].y = fmaf(p, v.y, acc[r].y);
                acc[r].z = fmaf(p, v.z, acc[r].z);
                acc[r].w = fmaf(p, v.w, acc[r].w);
            }
        }
        __syncthreads(); // everyone done reading s_s as p-values
        float4* part = (float4*)&s_s[0][0]; // [4 waves][8 rows][64 float4]
#pragma unroll
        for (int r = 0; r < QBLK; ++r) part[(kg * QBLK + r) * 64 + dl] = acc[r];
    }
    __syncthreads();

    // reduce 4 wave-partials -> attended rows (into q_s), apply 1/sum
    {
        const float4* part = (const float4*)&s_s[0][0];
        float4* att4 = (float4*)&q_s[0][0];
#pragma unroll
        for (int i = 0; i < 2; ++i) {
            const int idx = t + i * 256; // 0..511
            const int r = idx >> 6;
            const int dl = idx & 63;
            float4 s0 = part[(0 * QBLK + r) * 64 + dl];
            float4 s1 = part[(1 * QBLK + r) * 64 + dl];
            float4 s2 = part[(2 * QBLK + r) * 64 + dl];
            float4 s3 = part[(3 * QBLK + r) * 64 + dl];
            const float inv = inv_s[r];
            float4 a;
            a.x = (s0.x + s1.x + s2.x + s3.x) * inv;
            a.y = (s0.y + s1.y + s2.y + s3.y) * inv;
            a.z = (s0.z + s1.z + s2.z + s3.z) * inv;
            a.w = (s0.w + s1.w + s2.w + s3.w) * inv;
            att4[r * 64 + dl] = a;
        }
    }
    __syncthreads();

    // ---- Phase 4: out = att @ Wo.T + bo ----
    {
        const float4* wo4 = (const float4*)(Wo + (size_t)t * DD);
        const float4* att4 = (const float4*)&q_s[0][0];
        float acco[QBLK];
#pragma unroll
        for (int r = 0; r < QBLK; ++r) acco[r] = 0.f;

        for (int d4 = 0; d4 < DD / 4; ++d4) {
            float4 w = wo4[d4];
#pragma unroll
            for (int r = 0; r < QBLK; ++r) {
                float4 a = att4[r * 64 + d4]; // broadcast
                acco[r] = fmaf(a.x, w.x, acco[r]);
                acco[r] = fmaf(a.y, w.y, acco[r]);
                acco[r] = fmaf(a.z, w.z, acco[r]);
                acco[r] = fmaf(a.w, w.w, acco[r]);
            }
        }
        const float bov = bo[t];
#pragma unroll
        for (int r = 0; r < QBLK; ++r)
            out[(size_t)(rowbase + r) * DD + t] = acco[r] + bov;
    }
}

// ---------------------------------------------------------------------------
extern "C" void kernel_launch(void* const* d_in, const int* in_sizes, int n_in,
                              void* d_out, int out_size, void* d_ws, size_t ws_size,
                              hipStream_t stream) {
    const float* x  = (const float*)d_in[0];
    const float* Wq = (const float*)d_in[1];
    const float* bq = (const float*)d_in[2];
    const float* Wk = (const float*)d_in[3];
    const float* bk = (const float*)d_in[4];
    const float* Wv = (const float*)d_in[5];
    const float* bv = (const float*)d_in[6];
    const float* Wo = (const float*)d_in[7];
    const float* bo = (const float*)d_in[8];
    float* out = (float*)d_out;

    // workspace layout (floats): Q | K | V | qq | kk
    const size_t rows = (size_t)BB * SS;          // 2048
    float* Q  = (float*)d_ws;
    float* K  = Q + rows * DD;
    float* V  = K + rows * DD;
    float* qq = V + rows * DD;
    float* kk = qq + rows;

    const int nblk = (int)(rows / QBLK); // 256
    qkv_kernel<<<nblk, 256, 0, stream>>>(x, Wq, bq, Wk, bk, Wv, bv,
                                         Q, K, V, qq, kk);
    attn_kernel<<<nblk, 256, 0, stream>>>(Q, K, V, qq, kk, Wo, bo, out);
}

// Round 2
// 125.618 us; speedup vs baseline: 1.0362x; 1.0362x over previous
//
#include <hip/hip_runtime.h>

#define BB 2
#define SS 1024
#define DD 256
#define QBLK 4

// ---------------------------------------------------------------------------
// Kernel A: Q = x@Wq.T+bq (row-major), K^T (KT[b][d][s]), V = x@Wv.T+bv,
//           qq[row]=|Q_row|^2, kk[row]=|K_row|^2.
// One block = 4 rows. Thread t owns output column t for all 4 rows; weight
// row W*[t,:] is read once per block (L1-temporal across d4) and reused 4x.
// ---------------------------------------------------------------------------
__global__ __launch_bounds__(256, 2) void qkv_kernel(
    const float* __restrict__ x,
    const float* __restrict__ Wq, const float* __restrict__ bq,
    const float* __restrict__ Wk, const float* __restrict__ bk,
    const float* __restrict__ Wv, const float* __restrict__ bv,
    float* __restrict__ Q, float* __restrict__ KT, float* __restrict__ V,
    float* __restrict__ qq, float* __restrict__ kk)
{
    __shared__ float xs[QBLK][DD];
    __shared__ float redq[QBLK][4];
    __shared__ float redk[QBLK][4];

    const int t = threadIdx.x;
    const int row0 = blockIdx.x * QBLK;

    // stage 4 x-rows: 1024 floats = 256 float4, coalesced, one per thread
    {
        const float4* xg = (const float4*)(x + (size_t)row0 * DD);
        float4* xs4 = (float4*)&xs[0][0];
        xs4[t] = xg[t];
    }
    __syncthreads();

    float aq[QBLK], ak[QBLK], av[QBLK];
#pragma unroll
    for (int r = 0; r < QBLK; ++r) { aq[r] = 0.f; ak[r] = 0.f; av[r] = 0.f; }

    const float4* wq4 = (const float4*)(Wq + (size_t)t * DD);
    const float4* wk4 = (const float4*)(Wk + (size_t)t * DD);
    const float4* wv4 = (const float4*)(Wv + (size_t)t * DD);
    const float4* xsv = (const float4*)&xs[0][0]; // row r starts at r*64

    for (int d4 = 0; d4 < DD / 4; ++d4) {
        float4 wq = wq4[d4];
        float4 wk = wk4[d4];
        float4 wv = wv4[d4];
#pragma unroll
        for (int r = 0; r < QBLK; ++r) {
            float4 xv = xsv[r * (DD / 4) + d4]; // uniform address -> broadcast
            aq[r] = fmaf(xv.x, wq.x, aq[r]);
            aq[r] = fmaf(xv.y, wq.y, aq[r]);
            aq[r] = fmaf(xv.z, wq.z, aq[r]);
            aq[r] = fmaf(xv.w, wq.w, aq[r]);
            ak[r] = fmaf(xv.x, wk.x, ak[r]);
            ak[r] = fmaf(xv.y, wk.y, ak[r]);
            ak[r] = fmaf(xv.z, wk.z, ak[r]);
            ak[r] = fmaf(xv.w, wk.w, ak[r]);
            av[r] = fmaf(xv.x, wv.x, av[r]);
            av[r] = fmaf(xv.y, wv.y, av[r]);
            av[r] = fmaf(xv.z, wv.z, av[r]);
            av[r] = fmaf(xv.w, wv.w, av[r]);
        }
    }

    const float bqv = bq[t], bkv = bk[t], bvv = bv[t];
    float sq[QBLK], sk[QBLK];
    float kvv[QBLK];
#pragma unroll
    for (int r = 0; r < QBLK; ++r) {
        float qv = aq[r] + bqv;
        float kv = ak[r] + bkv;
        float vv = av[r] + bvv;
        Q[(size_t)(row0 + r) * DD + t] = qv;
        V[(size_t)(row0 + r) * DD + t] = vv;
        kvv[r] = kv;
        sq[r] = qv * qv;
        sk[r] = kv * kv;
    }
    // K transposed: KT[b][d=t][s0+r]; 4 consecutive s -> one float4 store
    {
        const int b = row0 >> 10;
        const int s0 = row0 & (SS - 1);
        float4 kt = make_float4(kvv[0], kvv[1], kvv[2], kvv[3]);
        float4* KT4 = (float4*)KT;
        KT4[(size_t)(b * DD + t) * (SS / 4) + (s0 >> 2)] = kt;
    }

    // block-reduce the 4 row norms
    const int wave = t >> 6;
    const int lane = t & 63;
#pragma unroll
    for (int r = 0; r < QBLK; ++r) {
        float vq = sq[r];
        float vk = sk[r];
#pragma unroll
        for (int o = 32; o > 0; o >>= 1) {
            vq += __shfl_xor(vq, o, 64);
            vk += __shfl_xor(vk, o, 64);
        }
        if (lane == 0) { redq[r][wave] = vq; redk[r][wave] = vk; }
    }
    __syncthreads();
    if (t < QBLK) {
        qq[row0 + t] = redq[t][0] + redq[t][1] + redq[t][2] + redq[t][3];
        kk[row0 + t] = redk[t][0] + redk[t][1] + redk[t][2] + redk[t][3];
    }
}

// ---------------------------------------------------------------------------
// Kernel B: fused attention + output projection. One block = 4 query rows.
// Phase 1: thread t owns k-columns 4t..4t+3; KT reads fully coalesced.
// Phase 2: wave w does the complete softmax of row w (no cross-wave reduce).
// Phase 3: wave w handles k in [256w, 256w+256), coalesced V, p broadcasts.
// Phase 4: out = att @ Wo.T + bo.
// Score storage p[r][k] (r-major): all accesses stride-16B/lane, conflict-free.
// ---------------------------------------------------------------------------
__global__ __launch_bounds__(256, 2) void attn_kernel(
    const float* __restrict__ Q, const float* __restrict__ KT,
    const float* __restrict__ V,
    const float* __restrict__ qq, const float* __restrict__ kk,
    const float* __restrict__ Wo, const float* __restrict__ bo,
    float* __restrict__ out)
{
    __shared__ float q_s[QBLK][DD];   // Q rows; reused as attended rows
    __shared__ float p_s[QBLK][SS];   // scores->exp(p); reused as PV partials
    __shared__ float qq_s[QBLK];
    __shared__ float inv_s[QBLK];

    const int t = threadIdx.x;
    const int w = t >> 6;
    const int lane = t & 63;
    const int b = blockIdx.x >> 8;            // 256 q-tiles per batch
    const int q0 = (blockIdx.x & 255) * QBLK;
    const int rowbase = b * SS + q0;

    // stage Q rows (coalesced) + norms
    {
        const float4* qg = (const float4*)(Q + (size_t)rowbase * DD);
        float4* qs4 = (float4*)&q_s[0][0];
        qs4[t] = qg[t];
        if (t < QBLK) qq_s[t] = qq[rowbase + t];
    }
    __syncthreads();

    const float inv_sqrt_d = 0.0625f; // 1/sqrt(256)
    float4* ps4 = (float4*)&p_s[0][0];

    // ---- Phase 1: scores; thread t owns k = 4t..4t+3 ----
    {
        const float4* KT4 = (const float4*)KT;
        const float4* qsv = (const float4*)&q_s[0][0];
        const int kbase = b * DD; // KT row base for this batch
        float dot[QBLK][4];
#pragma unroll
        for (int r = 0; r < QBLK; ++r)
#pragma unroll
            for (int j = 0; j < 4; ++j) dot[r][j] = 0.f;

        for (int g = 0; g < DD / 4; ++g) {
            // 4 consecutive d-rows of KT, coalesced float4 over k
            float4 kv0 = KT4[(size_t)(kbase + 4 * g + 0) * (SS / 4) + t];
            float4 kv1 = KT4[(size_t)(kbase + 4 * g + 1) * (SS / 4) + t];
            float4 kv2 = KT4[(size_t)(kbase + 4 * g + 2) * (SS / 4) + t];
            float4 kv3 = KT4[(size_t)(kbase + 4 * g + 3) * (SS / 4) + t];
#pragma unroll
            for (int r = 0; r < QBLK; ++r) {
                float4 qv = qsv[r * (DD / 4) + g]; // q[r][4g..4g+3], broadcast
                dot[r][0] = fmaf(qv.x, kv0.x, dot[r][0]);
                dot[r][1] = fmaf(qv.x, kv0.y, dot[r][1]);
                dot[r][2] = fmaf(qv.x, kv0.z, dot[r][2]);
                dot[r][3] = fmaf(qv.x, kv0.w, dot[r][3]);
                dot[r][0] = fmaf(qv.y, kv1.x, dot[r][0]);
                dot[r][1] = fmaf(qv.y, kv1.y, dot[r][1]);
                dot[r][2] = fmaf(qv.y, kv1.z, dot[r][2]);
                dot[r][3] = fmaf(qv.y, kv1.w, dot[r][3]);
                dot[r][0] = fmaf(qv.z, kv2.x, dot[r][0]);
                dot[r][1] = fmaf(qv.z, kv2.y, dot[r][1]);
                dot[r][2] = fmaf(qv.z, kv2.z, dot[r][2]);
                dot[r][3] = fmaf(qv.z, kv2.w, dot[r][3]);
                dot[r][0] = fmaf(qv.w, kv3.x, dot[r][0]);
                dot[r][1] = fmaf(qv.w, kv3.y, dot[r][1]);
                dot[r][2] = fmaf(qv.w, kv3.z, dot[r][2]);
                dot[r][3] = fmaf(qv.w, kv3.w, dot[r][3]);
            }
        }
        const float4 kk4 = ((const float4*)kk)[b * (SS / 4) + t];
#pragma unroll
        for (int r = 0; r < QBLK; ++r) {
            float4 s;
            s.x = -sqrtf(fmaxf(qq_s[r] + kk4.x - 2.f * dot[r][0], 0.f)) * inv_sqrt_d;
            s.y = -sqrtf(fmaxf(qq_s[r] + kk4.y - 2.f * dot[r][1], 0.f)) * inv_sqrt_d;
            s.z = -sqrtf(fmaxf(qq_s[r] + kk4.z - 2.f * dot[r][2], 0.f)) * inv_sqrt_d;
            s.w = -sqrtf(fmaxf(qq_s[r] + kk4.w - 2.f * dot[r][3], 0.f)) * inv_sqrt_d;
            ps4[r * (SS / 4) + t] = s; // coalesced, conflict-free
        }
    }
    __syncthreads();

    // ---- Phase 2: wave w = full softmax of row w ----
    {
        float4 v0 = ps4[w * (SS / 4) + lane];
        float4 v1 = ps4[w * (SS / 4) + lane + 64];
        float4 v2 = ps4[w * (SS / 4) + lane + 128];
        float4 v3 = ps4[w * (SS / 4) + lane + 192];
        float m = fmaxf(fmaxf(fmaxf(v0.x, v0.y), fmaxf(v0.z, v0.w)),
                        fmaxf(fmaxf(v1.x, v1.y), fmaxf(v1.z, v1.w)));
        m = fmaxf(m, fmaxf(fmaxf(v2.x, v2.y), fmaxf(v2.z, v2.w)));
        m = fmaxf(m, fmaxf(fmaxf(v3.x, v3.y), fmaxf(v3.z, v3.w)));
#pragma unroll
        for (int o = 32; o > 0; o >>= 1) m = fmaxf(m, __shfl_xor(m, o, 64));
        float sum = 0.f;
        float4 e;
        e.x = __expf(v0.x - m); e.y = __expf(v0.y - m);
        e.z = __expf(v0.z - m); e.w = __expf(v0.w - m);
        sum += e.x + e.y + e.z + e.w;
        ps4[w * (SS / 4) + lane] = e;
        e.x = __expf(v1.x - m); e.y = __expf(v1.y - m);
        e.z = __expf(v1.z - m); e.w = __expf(v1.w - m);
        sum += e.x + e.y + e.z + e.w;
        ps4[w * (SS / 4) + lane + 64] = e;
        e.x = __expf(v2.x - m); e.y = __expf(v2.y - m);
        e.z = __expf(v2.z - m); e.w = __expf(v2.w - m);
        sum += e.x + e.y + e.z + e.w;
        ps4[w * (SS / 4) + lane + 128] = e;
        e.x = __expf(v3.x - m); e.y = __expf(v3.y - m);
        e.z = __expf(v3.z - m); e.w = __expf(v3.w - m);
        sum += e.x + e.y + e.z + e.w;
        ps4[w * (SS / 4) + lane + 192] = e;
#pragma unroll
        for (int o = 32; o > 0; o >>= 1) sum += __shfl_xor(sum, o, 64);
        if (lane == 0) inv_s[w] = 1.f / sum;
    }
    __syncthreads();

    // ---- Phase 3: PV; wave w handles k in [256w, 256w+256) ----
    {
        const float4* V4 = (const float4*)V;
        const int vbase = b * SS;
        float4 acc[QBLK];
#pragma unroll
        for (int r = 0; r < QBLK; ++r) acc[r] = make_float4(0.f, 0.f, 0.f, 0.f);

        for (int kj4 = 0; kj4 < 64; ++kj4) {
            const int k0 = 256 * w + 4 * kj4;
            float4 v0 = V4[(size_t)(vbase + k0 + 0) * (DD / 4) + lane];
            float4 v1 = V4[(size_t)(vbase + k0 + 1) * (DD / 4) + lane];
            float4 v2 = V4[(size_t)(vbase + k0 + 2) * (DD / 4) + lane];
            float4 v3 = V4[(size_t)(vbase + k0 + 3) * (DD / 4) + lane];
#pragma unroll
            for (int r = 0; r < QBLK; ++r) {
                float4 p = ps4[r * (SS / 4) + 64 * w + kj4]; // uniform -> bcast
                acc[r].x = fmaf(p.x, v0.x, acc[r].x);
                acc[r].y = fmaf(p.x, v0.y, acc[r].y);
                acc[r].z = fmaf(p.x, v0.z, acc[r].z);
                acc[r].w = fmaf(p.x, v0.w, acc[r].w);
                acc[r].x = fmaf(p.y, v1.x, acc[r].x);
                acc[r].y = fmaf(p.y, v1.y, acc[r].y);
                acc[r].z = fmaf(p.y, v1.z, acc[r].z);
                acc[r].w = fmaf(p.y, v1.w, acc[r].w);
                acc[r].x = fmaf(p.z, v2.x, acc[r].x);
                acc[r].y = fmaf(p.z, v2.y, acc[r].y);
                acc[r].z = fmaf(p.z, v2.z, acc[r].z);
                acc[r].w = fmaf(p.z, v2.w, acc[r].w);
                acc[r].x = fmaf(p.w, v3.x, acc[r].x);
                acc[r].y = fmaf(p.w, v3.y, acc[r].y);
                acc[r].z = fmaf(p.w, v3.z, acc[r].z);
                acc[r].w = fmaf(p.w, v3.w, acc[r].w);
            }
        }
        __syncthreads(); // all waves done reading p_s
        float4* part = (float4*)&p_s[0][0]; // [4 waves][4 rows][64 float4]
#pragma unroll
        for (int r = 0; r < QBLK; ++r) part[(w * QBLK + r) * 64 + lane] = acc[r];
    }
    __syncthreads();

    // reduce 4 wave-partials -> attended rows (into q_s), apply 1/sum
    {
        const float4* part = (const float4*)&p_s[0][0];
        float4* att4 = (float4*)&q_s[0][0];
        const int r = t >> 6;  // 4 rows x 64 float4 = 256 threads exactly
        const int dl = t & 63;
        float4 s0 = part[(0 * QBLK + r) * 64 + dl];
        float4 s1 = part[(1 * QBLK + r) * 64 + dl];
        float4 s2 = part[(2 * QBLK + r) * 64 + dl];
        float4 s3 = part[(3 * QBLK + r) * 64 + dl];
        const float inv = inv_s[r];
        float4 a;
        a.x = (s0.x + s1.x + s2.x + s3.x) * inv;
        a.y = (s0.y + s1.y + s2.y + s3.y) * inv;
        a.z = (s0.z + s1.z + s2.z + s3.z) * inv;
        a.w = (s0.w + s1.w + s2.w + s3.w) * inv;
        att4[r * 64 + dl] = a;
    }
    __syncthreads();

    // ---- Phase 4: out = att @ Wo.T + bo ----
    {
        const float4* wo4 = (const float4*)(Wo + (size_t)t * DD);
        const float4* att4 = (const float4*)&q_s[0][0];
        float acco[QBLK];
#pragma unroll
        for (int r = 0; r < QBLK; ++r) acco[r] = 0.f;

        for (int d4 = 0; d4 < DD / 4; ++d4) {
            float4 wv = wo4[d4];
#pragma unroll
            for (int r = 0; r < QBLK; ++r) {
                float4 a = att4[r * 64 + d4]; // broadcast
                acco[r] = fmaf(a.x, wv.x, acco[r]);
                acco[r] = fmaf(a.y, wv.y, acco[r]);
                acco[r] = fmaf(a.z, wv.z, acco[r]);
                acco[r] = fmaf(a.w, wv.w, acco[r]);
            }
        }
        const float bov = bo[t];
#pragma unroll
        for (int r = 0; r < QBLK; ++r)
            out[(size_t)(rowbase + r) * DD + t] = acco[r] + bov;
    }
}

// ---------------------------------------------------------------------------
extern "C" void kernel_launch(void* const* d_in, const int* in_sizes, int n_in,
                              void* d_out, int out_size, void* d_ws, size_t ws_size,
                              hipStream_t stream) {
    const float* x  = (const float*)d_in[0];
    const float* Wq = (const float*)d_in[1];
    const float* bq = (const float*)d_in[2];
    const float* Wk = (const float*)d_in[3];
    const float* bk = (const float*)d_in[4];
    const float* Wv = (const float*)d_in[5];
    const float* bv = (const float*)d_in[6];
    const float* Wo = (const float*)d_in[7];
    const float* bo = (const float*)d_in[8];
    float* out = (float*)d_out;

    // workspace layout (floats): Q | KT | V | qq | kk
    const size_t rows = (size_t)BB * SS;          // 2048
    float* Q  = (float*)d_ws;
    float* KT = Q + rows * DD;
    float* V  = KT + rows * DD;
    float* qq = V + rows * DD;
    float* kk = qq + rows;

    const int nblk = (int)(rows / QBLK); // 512
    qkv_kernel<<<nblk, 256, 0, stream>>>(x, Wq, bq, Wk, bk, Wv, bv,
                                         Q, KT, V, qq, kk);
    attn_kernel<<<nblk, 256, 0, stream>>>(Q, KT, V, qq, kk, Wo, bo, out);
}

// Round 3
// 98.952 us; speedup vs baseline: 1.3154x; 1.2695x over previous
//
#include <hip/hip_runtime.h>

#define BB 2
#define SS 1024
#define DD 256
#define RB 8            // q-rows per tile (kernels A and B)
#define NCH 4           // number of k-chunks
#define KCH 256         // k-chunk size
#define RC 4            // rows per combine block

// ---------------------------------------------------------------------------
// Kernel A: one block = (8 rows) x (one of Q/K/V). grid = 256*3 = 768 blocks
// (3 blocks/CU). Thread t owns output column t for all 8 rows; weight row
// W[t,:] read once per block. Q,V stored row-major; K stored transposed
// KT[b][d][s]; row norms qq/kk computed in-block.
// ---------------------------------------------------------------------------
__global__ __launch_bounds__(256, 3) void qkv_kernel(
    const float* __restrict__ x,
    const float* __restrict__ Wq, const float* __restrict__ bq,
    const float* __restrict__ Wk, const float* __restrict__ bk,
    const float* __restrict__ Wv, const float* __restrict__ bv,
    float* __restrict__ Q, float* __restrict__ KT, float* __restrict__ V,
    float* __restrict__ qq, float* __restrict__ kk)
{
    __shared__ float xs[RB][DD];
    __shared__ float red[RB][4];

    const int t = threadIdx.x;
    const int mat = blockIdx.x % 3;          // 0=Q 1=K 2=V
    const int tile = blockIdx.x / 3;
    const int row0 = tile * RB;              // global row (includes batch)

    // stage 8 x-rows: 2048 floats = 512 float4
    {
        const float4* xg = (const float4*)(x + (size_t)row0 * DD);
        float4* xs4 = (float4*)&xs[0][0];
        xs4[t] = xg[t];
        xs4[t + 256] = xg[t + 256];
    }
    __syncthreads();

    const float* W = (mat == 0) ? Wq : (mat == 1) ? Wk : Wv;
    const float* bias = (mat == 0) ? bq : (mat == 1) ? bk : bv;

    float acc[RB];
#pragma unroll
    for (int r = 0; r < RB; ++r) acc[r] = 0.f;

    const float4* w4 = (const float4*)(W + (size_t)t * DD);
    const float4* xsv = (const float4*)&xs[0][0];

    for (int d4 = 0; d4 < DD / 4; ++d4) {
        float4 w = w4[d4];
#pragma unroll
        for (int r = 0; r < RB; ++r) {
            float4 xv = xsv[r * (DD / 4) + d4]; // uniform -> LDS broadcast
            acc[r] = fmaf(xv.x, w.x, acc[r]);
            acc[r] = fmaf(xv.y, w.y, acc[r]);
            acc[r] = fmaf(xv.z, w.z, acc[r]);
            acc[r] = fmaf(xv.w, w.w, acc[r]);
        }
    }

    const float bv_ = bias[t];
    float val[RB];
#pragma unroll
    for (int r = 0; r < RB; ++r) val[r] = acc[r] + bv_;

    if (mat == 2) {
#pragma unroll
        for (int r = 0; r < RB; ++r)
            V[(size_t)(row0 + r) * DD + t] = val[r];
        return;
    }

    // row norms (Q or K)
    const int wave = t >> 6;
    const int lane = t & 63;
#pragma unroll
    for (int r = 0; r < RB; ++r) {
        float s = val[r] * val[r];
#pragma unroll
        for (int o = 32; o > 0; o >>= 1) s += __shfl_xor(s, o, 64);
        if (lane == 0) red[r][wave] = s;
    }

    if (mat == 0) {
#pragma unroll
        for (int r = 0; r < RB; ++r)
            Q[(size_t)(row0 + r) * DD + t] = val[r];
        __syncthreads();
        if (t < RB) qq[row0 + t] = red[t][0] + red[t][1] + red[t][2] + red[t][3];
    } else {
        // KT[b][d=t][s0..s0+7]: two float4 stores
        const int b = row0 >> 10;
        const int s0 = row0 & (SS - 1);
        float4* KT4 = (float4*)KT;
        KT4[(size_t)(b * DD + t) * (SS / 4) + (s0 >> 2)] =
            make_float4(val[0], val[1], val[2], val[3]);
        KT4[(size_t)(b * DD + t) * (SS / 4) + (s0 >> 2) + 1] =
            make_float4(val[4], val[5], val[6], val[7]);
        __syncthreads();
        if (t < RB) kk[row0 + t] = red[t][0] + red[t][1] + red[t][2] + red[t][3];
    }
}

// ---------------------------------------------------------------------------
// Kernel B: partial attention. One block = (8 q-rows) x (256-k chunk).
// grid = 256 qtiles * 4 chunks = 1024 blocks (4/CU, 16 waves/CU).
// Scores are exp(-dist/16) with dist>=0 -> e in (0,1]: NO max-pass needed,
// chunks combine additively. Outputs: Opart[c][row][d] = sum_k e*V,
// esum[c][row] = sum_k e.
// Phase 1: thread t owns k-col s0+t (coalesced KT reads).
// Phase 2: PV; wave w owns k-subrange [64w,64w+64), lane owns d-col float4.
// LDS: smem 16KB aliased as {q_s 8KB | p_s 8KB} then as part[4][4][64]float4.
// ---------------------------------------------------------------------------
__global__ __launch_bounds__(256, 4) void attn_part_kernel(
    const float* __restrict__ Q, const float* __restrict__ KT,
    const float* __restrict__ V,
    const float* __restrict__ qq, const float* __restrict__ kk,
    float* __restrict__ Opart, float* __restrict__ esum)
{
    __shared__ float smem[4096];       // 16 KB
    __shared__ float qq_s[RB];
    __shared__ float es_part[4][RB];

    float* q_s = smem;                 // [RB][DD] = 2048 floats
    float* p_s = smem + RB * DD;       // [RB][KCH] = 2048 floats
    float4* part4 = (float4*)smem;     // aliased later: [4][4][64] float4

    const int t = threadIdx.x;
    const int w = t >> 6;
    const int lane = t & 63;
    const int qtile = blockIdx.x >> 2;
    const int c = blockIdx.x & 3;
    const int rowbase = qtile * RB;          // global row
    const int b = rowbase >> 10;             // batch
    const int s0 = c * KCH;                  // k-chunk start (within batch)

    // stage Q-tile + norms
    {
        const float4* qg = (const float4*)(Q + (size_t)rowbase * DD);
        float4* qs4 = (float4*)q_s;
        qs4[t] = qg[t];
        qs4[t + 256] = qg[t + 256];
        if (t < RB) qq_s[t] = qq[rowbase + t];
    }
    __syncthreads();

    // ---- Phase 1: scores for k = s0 + t ----
    {
        const float* ktp = KT + (size_t)(b * DD) * SS + (s0 + t);
        const float4* qs4 = (const float4*)q_s;
        float dot[RB];
#pragma unroll
        for (int r = 0; r < RB; ++r) dot[r] = 0.f;

        for (int d4 = 0; d4 < DD / 4; ++d4) {
            float k0 = ktp[(size_t)(4 * d4 + 0) * SS];
            float k1 = ktp[(size_t)(4 * d4 + 1) * SS];
            float k2 = ktp[(size_t)(4 * d4 + 2) * SS];
            float k3 = ktp[(size_t)(4 * d4 + 3) * SS];
#pragma unroll
            for (int r = 0; r < RB; ++r) {
                float4 qv = qs4[r * (DD / 4) + d4]; // broadcast
                dot[r] = fmaf(qv.x, k0, dot[r]);
                dot[r] = fmaf(qv.y, k1, dot[r]);
                dot[r] = fmaf(qv.z, k2, dot[r]);
                dot[r] = fmaf(qv.w, k3, dot[r]);
            }
        }
        const float kkv = kk[b * SS + s0 + t];
        float e[RB];
#pragma unroll
        for (int r = 0; r < RB; ++r) {
            float d2 = fmaxf(qq_s[r] + kkv - 2.f * dot[r], 0.f);
            e[r] = __expf(-sqrtf(d2) * 0.0625f);   // in (0,1] — safe, no max
            p_s[r * KCH + t] = e[r];
        }
        // per-wave esum partials
#pragma unroll
        for (int r = 0; r < RB; ++r) {
            float s = e[r];
#pragma unroll
            for (int o = 32; o > 0; o >>= 1) s += __shfl_xor(s, o, 64);
            if (lane == 0) es_part[w][r] = s;
        }
    }
    __syncthreads();

    if (t < RB)
        esum[(size_t)c * (BB * SS) + rowbase + t] =
            es_part[0][t] + es_part[1][t] + es_part[2][t] + es_part[3][t];

    // ---- Phase 2: PV; wave w -> k in [s0+64w, s0+64w+64), lane -> d-col f4
    float4 acc[RB];
#pragma unroll
    for (int r = 0; r < RB; ++r) acc[r] = make_float4(0.f, 0.f, 0.f, 0.f);
    {
        const float4* V4 = (const float4*)V;
        const size_t vrow0 = (size_t)(b * SS + s0 + 64 * w);
        for (int kj = 0; kj < 64; ++kj) {
            float4 v = V4[(vrow0 + kj) * (DD / 4) + lane];
#pragma unroll
            for (int r = 0; r < RB; ++r) {
                float p = p_s[r * KCH + 64 * w + kj]; // uniform -> broadcast
                acc[r].x = fmaf(p, v.x, acc[r].x);
                acc[r].y = fmaf(p, v.y, acc[r].y);
                acc[r].z = fmaf(p, v.z, acc[r].z);
                acc[r].w = fmaf(p, v.w, acc[r].w);
            }
        }
    }
    __syncthreads(); // p_s/q_s dead; smem now the partial buffer

    float4* Opart4 = (float4*)Opart;
    // pass A: rows 0..3
#pragma unroll
    for (int r = 0; r < 4; ++r) part4[(w * 4 + r) * 64 + lane] = acc[r];
    __syncthreads();
    {
        const int r = t >> 6;     // 0..3
        const int dl = t & 63;
        float4 s0v = part4[(0 * 4 + r) * 64 + dl];
        float4 s1v = part4[(1 * 4 + r) * 64 + dl];
        float4 s2v = part4[(2 * 4 + r) * 64 + dl];
        float4 s3v = part4[(3 * 4 + r) * 64 + dl];
        float4 o;
        o.x = s0v.x + s1v.x + s2v.x + s3v.x;
        o.y = s0v.y + s1v.y + s2v.y + s3v.y;
        o.z = s0v.z + s1v.z + s2v.z + s3v.z;
        o.w = s0v.w + s1v.w + s2v.w + s3v.w;
        Opart4[((size_t)c * (BB * SS) + rowbase + r) * (DD / 4) + dl] = o;
    }
    __syncthreads();
    // pass B: rows 4..7
#pragma unroll
    for (int r = 0; r < 4; ++r) part4[(w * 4 + r) * 64 + lane] = acc[4 + r];
    __syncthreads();
    {
        const int r = t >> 6;
        const int dl = t & 63;
        float4 s0v = part4[(0 * 4 + r) * 64 + dl];
        float4 s1v = part4[(1 * 4 + r) * 64 + dl];
        float4 s2v = part4[(2 * 4 + r) * 64 + dl];
        float4 s3v = part4[(3 * 4 + r) * 64 + dl];
        float4 o;
        o.x = s0v.x + s1v.x + s2v.x + s3v.x;
        o.y = s0v.y + s1v.y + s2v.y + s3v.y;
        o.z = s0v.z + s1v.z + s2v.z + s3v.z;
        o.w = s0v.w + s1v.w + s2v.w + s3v.w;
        Opart4[((size_t)c * (BB * SS) + rowbase + 4 + r) * (DD / 4) + dl] = o;
    }
}

// ---------------------------------------------------------------------------
// Kernel C: combine chunks + output projection. One block = 4 rows.
// grid = 512 blocks. att[r][t] = sum_c Opart[c][row][t]; denom = sum_c esum.
// out = (att/denom) @ Wo.T + bo, with 1/denom folded into the epilogue.
// ---------------------------------------------------------------------------
__global__ __launch_bounds__(256, 4) void combine_kernel(
    const float* __restrict__ Opart, const float* __restrict__ esum,
    const float* __restrict__ Wo, const float* __restrict__ bo,
    float* __restrict__ out)
{
    __shared__ float att_s[RC][DD];
    __shared__ float inv_s[RC];

    const int t = threadIdx.x;
    const int r0 = blockIdx.x * RC;   // global row

    if (t < RC) {
        float d = 0.f;
#pragma unroll
        for (int c = 0; c < NCH; ++c) d += esum[(size_t)c * (BB * SS) + r0 + t];
        inv_s[t] = 1.f / d;
    }
#pragma unroll
    for (int r = 0; r < RC; ++r) {
        float a = 0.f;
#pragma unroll
        for (int c = 0; c < NCH; ++c)
            a += Opart[((size_t)c * (BB * SS) + r0 + r) * DD + t];
        att_s[r][t] = a;
    }
    __syncthreads();

    const float4* wo4 = (const float4*)(Wo + (size_t)t * DD);
    const float4* att4 = (const float4*)&att_s[0][0];
    float acco[RC];
#pragma unroll
    for (int r = 0; r < RC; ++r) acco[r] = 0.f;

    for (int d4 = 0; d4 < DD / 4; ++d4) {
        float4 w = wo4[d4];
#pragma unroll
        for (int r = 0; r < RC; ++r) {
            float4 a = att4[r * (DD / 4) + d4]; // broadcast
            acco[r] = fmaf(a.x, w.x, acco[r]);
            acco[r] = fmaf(a.y, w.y, acco[r]);
            acco[r] = fmaf(a.z, w.z, acco[r]);
            acco[r] = fmaf(a.w, w.w, acco[r]);
        }
    }
    const float bov = bo[t];
#pragma unroll
    for (int r = 0; r < RC; ++r)
        out[(size_t)(r0 + r) * DD + t] = acco[r] * inv_s[r] + bov;
}

// ---------------------------------------------------------------------------
extern "C" void kernel_launch(void* const* d_in, const int* in_sizes, int n_in,
                              void* d_out, int out_size, void* d_ws, size_t ws_size,
                              hipStream_t stream) {
    const float* x  = (const float*)d_in[0];
    const float* Wq = (const float*)d_in[1];
    const float* bq = (const float*)d_in[2];
    const float* Wk = (const float*)d_in[3];
    const float* bk = (const float*)d_in[4];
    const float* Wv = (const float*)d_in[5];
    const float* bv = (const float*)d_in[6];
    const float* Wo = (const float*)d_in[7];
    const float* bo = (const float*)d_in[8];
    float* out = (float*)d_out;

    // ws layout (floats): Q | KT | V | qq | kk | esum | Opart
    const size_t rows = (size_t)BB * SS;            // 2048
    float* Q     = (float*)d_ws;
    float* KT    = Q + rows * DD;
    float* V     = KT + rows * DD;
    float* qq    = V + rows * DD;
    float* kk    = qq + rows;
    float* esum  = kk + rows;
    float* Opart = esum + (size_t)NCH * rows;       // NCH*rows*DD floats

    qkv_kernel<<<(int)(rows / RB) * 3, 256, 0, stream>>>(
        x, Wq, bq, Wk, bk, Wv, bv, Q, KT, V, qq, kk);
    attn_part_kernel<<<(int)(rows / RB) * NCH, 256, 0, stream>>>(
        Q, KT, V, qq, kk, Opart, esum);
    combine_kernel<<<(int)(rows / RC), 256, 0, stream>>>(
        Opart, esum, Wo, bo, out);
}

// Round 4
// 62.216 us; speedup vs baseline: 2.0921x; 1.5905x over previous
//
#include <hip/hip_runtime.h>
#include <hip/hip_bf16.h>

#define BB 2
#define SS 1024
#define DD 256
#define NCH 4           // k-chunks in attn
#define KCH 256         // k-chunk size
#define RC 4            // rows per combine block

typedef __attribute__((ext_vector_type(8))) short bf16x8;
typedef __attribute__((ext_vector_type(4))) float f32x4;

__device__ __forceinline__ unsigned short f2bf(float f) {
    __hip_bfloat16 h = __float2bfloat16(f);
    return *reinterpret_cast<unsigned short*>(&h);
}
__device__ __forceinline__ float bf2f(unsigned short u) {
    __hip_bfloat16 h;
    *reinterpret_cast<unsigned short*>(&h) = u;
    return __bfloat162float(h);
}

// ---------------------------------------------------------------------------
// Kernel 1: QKV projection via MFMA. grid = 128 rowtiles x 3 mats = 384.
// Block = 16 seq-rows x 256 out-cols for one of {Q,K,V}; wave w owns 64 cols.
// A-frag: lane(row=l%16, 8 contiguous d) from row-major fp32 x -> cvt bf16.
// B-frag: lane(col=l%16, 8 contiguous d) from row-major fp32 W -> cvt bf16.
// Both are coalesced 32B/lane loads -- no LDS staging, no scatter.
// Outputs: Qb,Kb row-major bf16; V in MFMA-B fragment layout (VB);
// qq/kk = row norms of the bf16-ROUNDED values (consistency with MFMA dots).
// ---------------------------------------------------------------------------
__global__ __launch_bounds__(256, 2) void qkv_mfma(
    const float* __restrict__ x,
    const float* __restrict__ Wq, const float* __restrict__ bq,
    const float* __restrict__ Wk, const float* __restrict__ bk,
    const float* __restrict__ Wv, const float* __restrict__ bv,
    unsigned short* __restrict__ Qb, unsigned short* __restrict__ Kb,
    unsigned short* __restrict__ VB,
    float* __restrict__ qq, float* __restrict__ kk)
{
    __shared__ float red[4][16];
    const int t = threadIdx.x;
    const int w = t >> 6, l = t & 63, lr = l & 15, lc = l >> 4;
    const int mat = blockIdx.x % 3;
    const int tile = blockIdx.x / 3;
    const int r0 = tile * 16;                 // global seq row (incl. batch)
    const int b = r0 >> 10;
    const int s_in_base = r0 & (SS - 1);

    const float* W    = (mat == 0) ? Wq : (mat == 1) ? Wk : Wv;
    const float* bias = (mat == 0) ? bq : (mat == 1) ? bk : bv;

    // A-frags from x, all 8 d-blocks (reused by 4 col-blocks)
    bf16x8 af[8];
#pragma unroll
    for (int db = 0; db < 8; ++db) {
        const float* xp = x + (size_t)(r0 + lr) * DD + db * 32 + 8 * lc;
        float4 f0 = *(const float4*)(xp);
        float4 f1 = *(const float4*)(xp + 4);
        bf16x8 a;
        a[0] = (short)f2bf(f0.x); a[1] = (short)f2bf(f0.y);
        a[2] = (short)f2bf(f0.z); a[3] = (short)f2bf(f0.w);
        a[4] = (short)f2bf(f1.x); a[5] = (short)f2bf(f1.y);
        a[6] = (short)f2bf(f1.z); a[7] = (short)f2bf(f1.w);
        af[db] = a;
    }

    float nrm[4] = {0.f, 0.f, 0.f, 0.f};

#pragma unroll
    for (int cb = 0; cb < 4; ++cb) {
        const int jb = 64 * w + 16 * cb;
        f32x4 acc = {0.f, 0.f, 0.f, 0.f};
#pragma unroll
        for (int db = 0; db < 8; ++db) {
            const float* wp = W + (size_t)(jb + lr) * DD + db * 32 + 8 * lc;
            float4 f0 = *(const float4*)(wp);
            float4 f1 = *(const float4*)(wp + 4);
            bf16x8 bf;
            bf[0] = (short)f2bf(f0.x); bf[1] = (short)f2bf(f0.y);
            bf[2] = (short)f2bf(f0.z); bf[3] = (short)f2bf(f0.w);
            bf[4] = (short)f2bf(f1.x); bf[5] = (short)f2bf(f1.y);
            bf[6] = (short)f2bf(f1.z); bf[7] = (short)f2bf(f1.w);
            acc = __builtin_amdgcn_mfma_f32_16x16x32_bf16(af[db], bf, acc, 0, 0, 0);
        }
        const float bv_ = bias[jb + lr];
#pragma unroll
        for (int r = 0; r < 4; ++r) {
            const int srow = r0 + lc * 4 + r;     // C/D: row=(l>>4)*4+r, col=l%16
            const float v = acc[r] + bv_;
            const unsigned short h = f2bf(v);
            if (mat == 0) {
                Qb[(size_t)srow * DD + jb + lr] = h;
                const float hv = bf2f(h); nrm[r] += hv * hv;
            } else if (mat == 1) {
                Kb[(size_t)srow * DD + jb + lr] = h;
                const float hv = bf2f(h); nrm[r] += hv * hv;
            } else {
                // VB layout: tile(b, kb32=s/32, db16=d/16) of 1024B;
                // lane (kslot*16 + d%16) holds 8 bf16 for k=kb32*32+kslot*8+jj
                const int s_in = s_in_base + lc * 4 + r;
                const int kb32 = s_in >> 5;
                const int kslot = (s_in >> 3) & 3;
                const int jj = s_in & 7;
                const int db16 = 4 * w + cb;
                const size_t off = ((size_t)((b * 32 + kb32) * 16 + db16) << 9)
                                 + ((kslot * 16 + lr) << 3) + jj;
                VB[off] = h;
            }
        }
    }

    if (mat < 2) {
#pragma unroll
        for (int r = 0; r < 4; ++r) {
            float n = nrm[r];
#pragma unroll
            for (int m = 1; m < 16; m <<= 1) n += __shfl_xor(n, m, 64);
            if (lr == 0) red[w][lc * 4 + r] = n;
        }
        __syncthreads();
        if (t < 16) {
            const float s = red[0][t] + red[1][t] + red[2][t] + red[3][t];
            if (mat == 0) qq[r0 + t] = s;
            else          kk[r0 + t] = s;
        }
    }
}

// ---------------------------------------------------------------------------
// Kernel 2: partial attention via MFMA. grid = 128 qtiles x NCH = 512.
// Block = 16 q-rows x 256-k chunk; 4 waves.
// QK^T: wave w owns k-cols [64w,64w+64): per k-block 8 MFMA over d.
// exp(-dist/16) in (0,1] -> no max pass; chunks combine additively.
// P stored in LDS bf16 [16][256] with XOR swizzle (G4 bank fix).
// PV: wave w owns d-cols [64w,64w+64): A=P (swizzled ds_read_b128),
// B=VB (coalesced 16B/lane), 8 k-iters x 4 d-blocks MFMA.
// ---------------------------------------------------------------------------
__global__ __launch_bounds__(256, 2) void attn_part_mfma(
    const unsigned short* __restrict__ Qb, const unsigned short* __restrict__ Kb,
    const unsigned short* __restrict__ VB,
    const float* __restrict__ qq, const float* __restrict__ kk,
    float* __restrict__ Opart, float* __restrict__ esum)
{
    __shared__ unsigned short P_s[16 * 256];   // 8 KB, XOR-swizzled
    __shared__ float kk_s[KCH];
    __shared__ float qq_s[16];
    __shared__ float es_red[4][16];

    const int t = threadIdx.x;
    const int w = t >> 6, l = t & 63, lr = l & 15, lc = l >> 4;
    const int qtile = blockIdx.x >> 2;
    const int c = blockIdx.x & 3;
    const int rowbase = qtile * 16;            // global row
    const int b = rowbase >> 10;
    const int s0 = c * KCH;                    // chunk start within batch

    kk_s[t] = kk[b * SS + s0 + t];
    if (t < 16) qq_s[t] = qq[rowbase + t];

    // Q A-frags: lane(row=l%16, 8 contiguous d), held in regs for the block
    bf16x8 qf[8];
#pragma unroll
    for (int db = 0; db < 8; ++db)
        qf[db] = *(const bf16x8*)(Qb + (size_t)(rowbase + lr) * DD + db * 32 + 8 * lc);

    __syncthreads();

    // ---- QK^T + exp ----
    float psum[4] = {0.f, 0.f, 0.f, 0.f};
#pragma unroll
    for (int kbi = 0; kbi < 4; ++kbi) {
        const int kb = 64 * w + 16 * kbi;
        f32x4 acc = {0.f, 0.f, 0.f, 0.f};
#pragma unroll
        for (int db = 0; db < 8; ++db) {
            bf16x8 kf = *(const bf16x8*)(
                Kb + (size_t)(b * SS + s0 + kb + lr) * DD + db * 32 + 8 * lc);
            acc = __builtin_amdgcn_mfma_f32_16x16x32_bf16(qf[db], kf, acc, 0, 0, 0);
        }
        const int kcol = kb + lr;
        const float kkv = kk_s[kcol];
#pragma unroll
        for (int r = 0; r < 4; ++r) {
            const int qi = lc * 4 + r;
            const float d2 = fmaxf(qq_s[qi] + kkv - 2.f * acc[r], 0.f);
            const float e = __expf(-sqrtf(d2) * 0.0625f);
            psum[r] += e;
            P_s[qi * 256 + (kcol ^ ((qi & 7) << 3))] = f2bf(e);
        }
    }
    // per-row e-sums: reduce across l%16, then across waves via LDS
#pragma unroll
    for (int r = 0; r < 4; ++r) {
        float s = psum[r];
#pragma unroll
        for (int m = 1; m < 16; m <<= 1) s += __shfl_xor(s, m, 64);
        if (lr == 0) es_red[w][lc * 4 + r] = s;
    }
    __syncthreads();
    if (t < 16)
        esum[(size_t)c * (BB * SS) + rowbase + t] =
            es_red[0][t] + es_red[1][t] + es_red[2][t] + es_red[3][t];

    // ---- PV ----
    f32x4 acc2[4];
#pragma unroll
    for (int i = 0; i < 4; ++i) acc2[i] = (f32x4){0.f, 0.f, 0.f, 0.f};

#pragma unroll
    for (int ki = 0; ki < 8; ++ki) {
        // A = P: lane(row q=l%16, k = 32ki + 8*(l>>4) + j), swizzled read
        bf16x8 pf = *(const bf16x8*)(
            P_s + lr * 256 + ((32 * ki + 8 * lc) ^ ((lr & 7) << 3)));
        const size_t tbase =
            ((size_t)((b * 32 + c * 8 + ki) * 16 + 4 * w) << 9) + l * 8;
#pragma unroll
        for (int dbi = 0; dbi < 4; ++dbi) {
            bf16x8 vf = *(const bf16x8*)(VB + tbase + ((size_t)dbi << 9));
            acc2[dbi] = __builtin_amdgcn_mfma_f32_16x16x32_bf16(pf, vf, acc2[dbi], 0, 0, 0);
        }
    }
#pragma unroll
    for (int dbi = 0; dbi < 4; ++dbi)
#pragma unroll
        for (int r = 0; r < 4; ++r)
            Opart[((size_t)c * (BB * SS) + rowbase + lc * 4 + r) * DD
                  + 64 * w + 16 * dbi + lr] = acc2[dbi][r];
}

// ---------------------------------------------------------------------------
// Kernel 3: combine chunks + output projection (unchanged from round 3).
// ---------------------------------------------------------------------------
__global__ __launch_bounds__(256, 4) void combine_kernel(
    const float* __restrict__ Opart, const float* __restrict__ esum,
    const float* __restrict__ Wo, const float* __restrict__ bo,
    float* __restrict__ out)
{
    __shared__ float att_s[RC][DD];
    __shared__ float inv_s[RC];

    const int t = threadIdx.x;
    const int r0 = blockIdx.x * RC;   // global row

    if (t < RC) {
        float d = 0.f;
#pragma unroll
        for (int c = 0; c < NCH; ++c) d += esum[(size_t)c * (BB * SS) + r0 + t];
        inv_s[t] = 1.f / d;
    }
#pragma unroll
    for (int r = 0; r < RC; ++r) {
        float a = 0.f;
#pragma unroll
        for (int c = 0; c < NCH; ++c)
            a += Opart[((size_t)c * (BB * SS) + r0 + r) * DD + t];
        att_s[r][t] = a;
    }
    __syncthreads();

    const float4* wo4 = (const float4*)(Wo + (size_t)t * DD);
    const float4* att4 = (const float4*)&att_s[0][0];
    float acco[RC];
#pragma unroll
    for (int r = 0; r < RC; ++r) acco[r] = 0.f;

    for (int d4 = 0; d4 < DD / 4; ++d4) {
        float4 w = wo4[d4];
#pragma unroll
        for (int r = 0; r < RC; ++r) {
            float4 a = att4[r * (DD / 4) + d4]; // broadcast
            acco[r] = fmaf(a.x, w.x, acco[r]);
            acco[r] = fmaf(a.y, w.y, acco[r]);
            acco[r] = fmaf(a.z, w.z, acco[r]);
            acco[r] = fmaf(a.w, w.w, acco[r]);
        }
    }
    const float bov = bo[t];
#pragma unroll
    for (int r = 0; r < RC; ++r)
        out[(size_t)(r0 + r) * DD + t] = acco[r] * inv_s[r] + bov;
}

// ---------------------------------------------------------------------------
extern "C" void kernel_launch(void* const* d_in, const int* in_sizes, int n_in,
                              void* d_out, int out_size, void* d_ws, size_t ws_size,
                              hipStream_t stream) {
    const float* x  = (const float*)d_in[0];
    const float* Wq = (const float*)d_in[1];
    const float* bq = (const float*)d_in[2];
    const float* Wk = (const float*)d_in[3];
    const float* bk = (const float*)d_in[4];
    const float* Wv = (const float*)d_in[5];
    const float* bv = (const float*)d_in[6];
    const float* Wo = (const float*)d_in[7];
    const float* bo = (const float*)d_in[8];
    float* out = (float*)d_out;

    // ws layout: Qb | Kb | VB (bf16, 1MB each) | qq | kk | esum | Opart (fp32)
    const size_t rows = (size_t)BB * SS;            // 2048
    unsigned short* Qb = (unsigned short*)d_ws;
    unsigned short* Kb = Qb + rows * DD;
    unsigned short* VB = Kb + rows * DD;
    float* qq    = (float*)(VB + rows * DD);
    float* kk    = qq + rows;
    float* esum  = kk + rows;
    float* Opart = esum + (size_t)NCH * rows;       // NCH*rows*DD floats

    qkv_mfma<<<(int)(rows / 16) * 3, 256, 0, stream>>>(
        x, Wq, bq, Wk, bk, Wv, bv, Qb, Kb, VB, qq, kk);
    attn_part_mfma<<<(int)(rows / 16) * NCH, 256, 0, stream>>>(
        Qb, Kb, VB, qq, kk, Opart, esum);
    combine_kernel<<<(int)(rows / RC), 256, 0, stream>>>(
        Opart, esum, Wo, bo, out);
}